// Round 11
// baseline (38.629 us; speedup 1.0000x reference)
//
#include <hip/hip_runtime.h>
#include <stdint.h>

#define NTYPES 12
#define EMB 128
#define KNN 30
#define SEPS_F 1e-6f
#define LEPS_F 1e6f
#define NATOMS 4800
#define GROUPS 19           // 4-item groups per lane (76 items incl 1 stored pad)
#define PADN 4864           // GROUPS*256 floats per axis per batch
#define CAPH 64             // per-half candidate cap
#define ROWS_PB 4           // rows per block (4 waves: 2 row-pairs x 2 halves)
#define SENT16 0x7F7Fu      // bucket sentinel for masked items

typedef unsigned long long ull;
typedef ull ull2 __attribute__((ext_vector_type(2)));
typedef float f32x2 __attribute__((ext_vector_type(2)));
typedef float f32x4 __attribute__((ext_vector_type(4)));

// ---- packed f32 ops (VOP3P, 2x rate) ----
__device__ __forceinline__ f32x2 pk_add(f32x2 a, f32x2 b) {
    f32x2 d; asm("v_pk_add_f32 %0, %1, %2" : "=v"(d) : "v"(a), "v"(b)); return d;
}
__device__ __forceinline__ f32x2 pk_mul(f32x2 a, f32x2 b) {
    f32x2 d; asm("v_pk_mul_f32 %0, %1, %2" : "=v"(d) : "v"(a), "v"(b)); return d;
}
__device__ __forceinline__ f32x2 pk_fma(f32x2 a, f32x2 b, f32x2 c) {
    f32x2 d; asm("v_pk_fma_f32 %0, %1, %2, %3" : "=v"(d) : "v"(a), "v"(b), "v"(c)); return d;
}
__device__ __forceinline__ unsigned pk_min_u16(unsigned a, unsigned b) {
    unsigned d; asm("v_pk_min_u16 %0, %1, %2" : "=v"(d) : "v"(a), "v"(b)); return d;
}

// packed filter d2 for 2 items (FMA ok: +2-bucket margin covers vs exact-rn)
__device__ __forceinline__ f32x2 d2pk(f32x2 x, f32x2 y, f32x2 z,
                                      f32x2 nqx, f32x2 nqy, f32x2 nqz) {
    f32x2 dx = pk_add(x, nqx), dy = pk_add(y, nqy), dz = pk_add(z, nqz);
    return pk_fma(dx, dx, pk_fma(dy, dy, pk_mul(dz, dz)));
}

// pack top-16 bits of two f32s: lo16 = even item (v.x), hi16 = odd item (v.y)
__device__ __forceinline__ unsigned bu(f32x2 v) {
    return __builtin_amdgcn_perm(__float_as_uint(v.y), __float_as_uint(v.x),
                                 0x07060302u);
}

// exact d2: plain rn ops, matches numpy bit-for-bit
__device__ __forceinline__ unsigned d2x(float x, float y, float z,
                                        float qx, float qy, float qz) {
    float dx = __fsub_rn(x, qx), dy = __fsub_rn(y, qy), dz = __fsub_rn(z, qz);
    float d2 = __fadd_rn(__fadd_rn(__fmul_rn(dx, dx), __fmul_rn(dy, dy)),
                         __fmul_rn(dz, dz));
    return __float_as_uint(d2);
}

// ---------------- prep (blocks 0..B-1) + SoA transpose (rest) — proven ----------------
__global__ __launch_bounds__(256) void prep_soa_kernel(const float* __restrict__ mask,
                                                       const float* __restrict__ w,
                                                       const float* __restrict__ scale,
                                                       const float* __restrict__ shift,
                                                       const float* __restrict__ coords,
                                                       float* __restrict__ cnt_all,
                                                       float* __restrict__ Aa,
                                                       float* __restrict__ Bb,
                                                       float* __restrict__ soa,
                                                       int B, int N) {
    if ((int)blockIdx.x < B) {
        __shared__ float lc[NTYPES];
        __shared__ float ltot;
        const int b = blockIdx.x;
        const int t = threadIdx.x;
        if (t < NTYPES) lc[t] = 0.f;
        if (t == 0) ltot = 0.f;
        __syncthreads();
        float s0 = 0.f, s1 = 0.f, s2 = 0.f, tot = 0.f;
        const float* mb = mask + (size_t)b * N;
#pragma unroll
        for (int base = 0; base < 21; base += 3) {
            int n0 = t + 256 * base;
            if (n0 < N) { float m = mb[n0]; s0 += m; tot += m; }
            int n1 = t + 256 * (base + 1);
            if (n1 < N) { float m = mb[n1]; s1 += m; tot += m; }
            int n2 = t + 256 * (base + 2);
            if (n2 < N) { float m = mb[n2]; s2 += m; tot += m; }
        }
        atomicAdd(&lc[t % NTYPES], s0);
        atomicAdd(&lc[(t + 4) % NTYPES], s1);
        atomicAdd(&lc[(t + 8) % NTYPES], s2);
        for (int s = 32; s >= 1; s >>= 1) tot += __shfl_xor(tot, s, 64);
        if ((t & 63) == 0) atomicAdd(&ltot, tot);
        __syncthreads();
        if (t < EMB) {
            const int d = t;
            float cnt = ltot;
            float c = (cnt == 0.f) ? 1.f : cnt;
            float mean = 0.f;
#pragma unroll
            for (int tt = 0; tt < NTYPES; ++tt) mean += w[tt * EMB + d] * lc[tt];
            mean /= c;
            float S = 0.f;
#pragma unroll
            for (int tt = 0; tt < NTYPES; ++tt) {
                float dv = w[tt * EMB + d] - mean;
                S += lc[tt] * dv * dv;
            }
            S += ((float)N - cnt) * mean * mean;
            float stdv = sqrtf(S / c + SEPS_F);
            float g = scale[d] / stdv;
            Aa[b * EMB + d] = g;
            Bb[b * EMB + d] = shift[d] - mean * g;
        }
        if (t == 0) cnt_all[b] = ltot;
    } else {
        int idx = blockIdx.x - B;
        const int b = idx / GROUPS;
        const int chunk = idx % GROUPS;
        const int j = chunk * 256 + threadIdx.x;   // 0..PADN-1
        float x, y, z;
        int slot;
        if (j < N) {
            int t = j >> 6, l = j & 63;
            slot = (t >> 2) * 256 + l * 4 + (t & 3);
            const float* cp = coords + ((size_t)b * N + j) * 3;
            x = cp[0]; y = cp[1]; z = cp[2];
        } else {
            int l = j - N;                          // stored pad item t = 75
            slot = (GROUPS - 1) * 256 + l * 4 + 3;
            x = y = z = 1.0e30f;                    // d2 -> +inf (bucket 0x7F80)
        }
        float* base = soa + (size_t)b * 3 * PADN;
        base[0 * PADN + slot] = x;
        base[1 * PADN + slot] = y;
        base[2 * PADN + slot] = z;
    }
}

// ---------------- exact 30-NN: 4 waves = 2 row-pairs x 2 halves ----------------
__global__ __launch_bounds__(256) void knn_kernel(const float* __restrict__ coords,
                                                  const float* __restrict__ soa,
                                                  const float* __restrict__ mask,
                                                  const float* __restrict__ cnt_all,
                                                  const float* __restrict__ w,
                                                  const float* __restrict__ Aa,
                                                  const float* __restrict__ Bb,
                                                  float* __restrict__ out0,
                                                  float* __restrict__ outd,
                                                  float* __restrict__ outi,
                                                  int B, int N) {
    __shared__ unsigned short lmx[ROWS_PB][2][64];  // lane-min buckets
    __shared__ unsigned candj[ROWS_PB][2][CAPH];    // candidate atom indices
    __shared__ int cnts[ROWS_PB][2];
    __shared__ __align__(16) ull keysS[ROWS_PB][2 * CAPH];  // exact keys for rank

    const int wv = threadIdx.x >> 6;
    const int lane = threadIdx.x & 63;
    const int pr = wv >> 1;                  // row-pair within block
    const int h = wv & 1;                    // item half
    const int r0 = blockIdx.x * ROWS_PB;
    const int b = r0 / N;                    // N % ROWS_PB == 0
    const int i0 = r0 - b * N;
    const int iA = i0 + 2 * pr;
    const int iB = iA + 1;

    const float* cb = coords + (size_t)b * N * 3;
    const float* mb = mask + (size_t)b * N;
    const bool allOnes = (cnt_all[b] == (float)N);

    // ---- fused embedding write for phase-E row (moved to top: latency overlaps
    //      the filter phase below; float2/lane) ----
    const int iE = i0 + wv;
    const float miE = mb[iE];
    {
        const int d0 = lane * 2;
        const float2 wvv = *(const float2*)(w + (iE % NTYPES) * EMB + d0);
        const float2 av = *(const float2*)(Aa + b * EMB + d0);
        const float2 bv2 = *(const float2*)(Bb + b * EMB + d0);
        float2 o;
        o.x = (wvv.x * miE * av.x + bv2.x) * miE;
        o.y = (wvv.y * miE * av.y + bv2.y) * miE;
        *(float2*)(out0 + ((size_t)b * N + iE) * EMB + d0) = o;
    }

    const float qxA = cb[iA * 3], qyA = cb[iA * 3 + 1], qzA = cb[iA * 3 + 2];
    const float qxB = cb[iB * 3], qyB = cb[iB * 3 + 1], qzB = cb[iB * 3 + 2];
    const f32x2 nqxA = {-qxA, -qxA}, nqyA = {-qyA, -qyA}, nqzA = {-qzA, -qzA};
    const f32x2 nqxB = {-qxB, -qxB}, nqyB = {-qyB, -qyB}, nqzB = {-qzB, -qzB};

    const float* xs = soa + (size_t)b * 3 * PADN;
    const float* ys = xs + PADN;
    const float* zs = ys + PADN;
    const int loff = lane << 2;
    const int gbase = h ? 10 : 0;
    const int tbase = 4 * gbase;             // first item index of this half

    unsigned pkA[20], pkB[20];
    unsigned lmA2 = 0xFFFFFFFFu, lmB2 = 0xFFFFFFFFu;

#define PROC_GROUP(P, S0, S1)                                                     \
    {                                                                             \
        const int g = gbase + (P);                                                \
        const f32x4 xv = *(const f32x4*)(xs + g * 256 + loff);                    \
        const f32x4 yv = *(const f32x4*)(ys + g * 256 + loff);                    \
        const f32x4 zv = *(const f32x4*)(zs + g * 256 + loff);                    \
        const f32x2 xlo = {xv.x, xv.y}, xhi = {xv.z, xv.w};                       \
        const f32x2 ylo = {yv.x, yv.y}, yhi = {yv.z, yv.w};                       \
        const f32x2 zlo = {zv.x, zv.y}, zhi = {zv.z, zv.w};                       \
        unsigned a01 = bu(d2pk(xlo, ylo, zlo, nqxA, nqyA, nqzA));                 \
        unsigned a23 = bu(d2pk(xhi, yhi, zhi, nqxA, nqyA, nqzA));                 \
        unsigned b01 = bu(d2pk(xlo, ylo, zlo, nqxB, nqyB, nqzB));                 \
        unsigned b23 = bu(d2pk(xhi, yhi, zhi, nqxB, nqyB, nqzB));                 \
        if (!allOnes) {                                                           \
            const int t0 = 4 * g;                                                 \
            int j0 = (t0 + 0) * 64 + lane;                                        \
            int j1 = (t0 + 1) * 64 + lane;                                        \
            int j2 = (t0 + 2) * 64 + lane;                                        \
            int j3 = (t0 + 3) * 64 + lane;                                        \
            if (j0 < N && mb[j0] == 0.f) { a01 = (a01 & 0xFFFF0000u) | SENT16;    \
                                           b01 = (b01 & 0xFFFF0000u) | SENT16; }  \
            if (j1 < N && mb[j1] == 0.f) { a01 = (a01 & 0xFFFFu) | (SENT16 << 16);\
                                           b01 = (b01 & 0xFFFFu) | (SENT16 << 16);}\
            if (j2 < N && mb[j2] == 0.f) { a23 = (a23 & 0xFFFF0000u) | SENT16;    \
                                           b23 = (b23 & 0xFFFF0000u) | SENT16; }  \
            if (j3 < N && mb[j3] == 0.f) { a23 = (a23 & 0xFFFFu) | (SENT16 << 16);\
                                           b23 = (b23 & 0xFFFFu) | (SENT16 << 16);}\
        }                                                                         \
        lmA2 = pk_min_u16(pk_min_u16(lmA2, a01), a23);                            \
        lmB2 = pk_min_u16(pk_min_u16(lmB2, b01), b23);                            \
        pkA[S0] = a01; pkA[S1] = a23;                                             \
        pkB[S0] = b01; pkB[S1] = b23;                                             \
    }

    PROC_GROUP(0, 0, 1)   PROC_GROUP(1, 2, 3)   PROC_GROUP(2, 4, 5)
    PROC_GROUP(3, 6, 7)   PROC_GROUP(4, 8, 9)   PROC_GROUP(5, 10, 11)
    PROC_GROUP(6, 12, 13) PROC_GROUP(7, 14, 15) PROC_GROUP(8, 16, 17)
    if (h == 0) {
        PROC_GROUP(9, 18, 19)
    } else {
        pkA[18] = pkA[19] = 0xFFFFFFFFu;   // virtual pad pairs, never selected
        pkB[18] = pkB[19] = 0xFFFFFFFFu;
    }
#undef PROC_GROUP

    unsigned lmA16 = lmA2 & 0xFFFFu; { unsigned t2 = lmA2 >> 16; if (t2 < lmA16) lmA16 = t2; }
    unsigned lmB16 = lmB2 & 0xFFFFu; { unsigned t2 = lmB2 >> 16; if (t2 < lmB16) lmB16 = t2; }
    lmx[2 * pr][h][lane] = (unsigned short)lmA16;
    lmx[2 * pr + 1][h][lane] = (unsigned short)lmB16;
    __syncthreads();
    const unsigned ptA = lmx[2 * pr][h ^ 1][lane];
    const unsigned ptB = lmx[2 * pr + 1][h ^ 1][lane];

    // ---- dual certificate: 31st smallest of 128 lane-mins, 15 fixed iters ----
    unsigned loA = 0, hiA = 0x7F80u, loB = 0, hiB = 0x7F80u;
    for (int it = 0; it < 15; ++it) {
        unsigned mA = (loA + hiA) >> 1, mB = (loB + hiB) >> 1;
        int cA = __popcll(__ballot(lmA16 <= mA)) + __popcll(__ballot(ptA <= mA));
        int cB = __popcll(__ballot(lmB16 <= mB)) + __popcll(__ballot(ptB <= mB));
        if (cA >= 31) hiA = mA; else loA = mA + 1;
        if (cB >= 31) hiB = mB; else loB = mB + 1;
    }
    const unsigned TsA = hiA + 2, TsB = hiB + 2;   // +2: FMA-vs-exact margin

    // ---- compact (ascending j within half), rows A then B ----
    const ull lmaskLT = (1ull << lane) - 1ull;
    {
        unsigned* dst = candj[2 * pr][h];
        int c = 0;
#pragma unroll
        for (int p = 0; p < 20; ++p) {
            unsigned reg = pkA[p];
            bool pe = (reg & 0xFFFFu) <= TsA;
            ull be = __ballot(pe);
            if (pe) {
                int pos = c + __popcll(be & lmaskLT);
                if (pos < CAPH) dst[pos] = (unsigned)((tbase + 2 * p) * 64 + lane);
            }
            c += __popcll(be);
            bool po = (reg >> 16) <= TsA;
            ull bo = __ballot(po);
            if (po) {
                int pos = c + __popcll(bo & lmaskLT);
                if (pos < CAPH) dst[pos] = (unsigned)((tbase + 2 * p + 1) * 64 + lane);
            }
            c += __popcll(bo);
        }
        if (lane == 0) cnts[2 * pr][h] = (c > CAPH) ? CAPH : c;
    }
    {
        unsigned* dst = candj[2 * pr + 1][h];
        int c = 0;
#pragma unroll
        for (int p = 0; p < 20; ++p) {
            unsigned reg = pkB[p];
            bool pe = (reg & 0xFFFFu) <= TsB;
            ull be = __ballot(pe);
            if (pe) {
                int pos = c + __popcll(be & lmaskLT);
                if (pos < CAPH) dst[pos] = (unsigned)((tbase + 2 * p) * 64 + lane);
            }
            c += __popcll(be);
            bool po = (reg >> 16) <= TsB;
            ull bo = __ballot(po);
            if (po) {
                int pos = c + __popcll(bo & lmaskLT);
                if (pos < CAPH) dst[pos] = (unsigned)((tbase + 2 * p + 1) * 64 + lane);
            }
            c += __popcll(bo);
        }
        if (lane == 0) cnts[2 * pr + 1][h] = (c > CAPH) ? CAPH : c;
    }
    __syncthreads();

    // ================= phase E: wave wv owns row r0+wv entirely =================
    const int lr = wv;
    const int row = r0 + lr;
    const int i = iE;
    const float mi = miE;

    if (mi == 0.f) {    // masked row: forced outputs (after last barrier -> safe)
        if (lane < KNN) {
            size_t o0 = (size_t)row * KNN + lane;
            outd[o0] = LEPS_F;
            outi[o0] = -1.f;
        }
        return;
    }

    const int c0 = cnts[lr][0];
    const int ct = c0 + cnts[lr][1];        // 31 <= ct <= 128
    const float qx = cb[i * 3], qy = cb[i * 3 + 1], qz = cb[i * 3 + 2];

    // ---- exact keys (reference rounding) into LDS; coords via L1-hot SoA ----
    ull* kb = keysS[lr];
    for (int ci = lane; ci < ct; ci += 64) {
        unsigned j = (ci < c0) ? candj[lr][0][ci] : candj[lr][1][ci - c0];
        ull key = ~0ull;
        if (j < (unsigned)N) {
            int t = (int)(j >> 6), l = (int)(j & 63u);
            int sd = ((t >> 2) << 8) + (l << 2) + (t & 3);
            unsigned db = d2x(xs[sd], ys[sd], zs[sd], qx, qy, qz);
            bool bad = (j == (unsigned)i);
            if (!allOnes) {                       // real branch: skip mb load
                if (mb[j] == 0.f) bad = true;
            }
            float dist = bad ? LEPS_F
                             : __fsqrt_rn(__fadd_rn(__uint_as_float(db), SEPS_F));
            key = ((ull)__float_as_uint(dist) << 32) | j;
        }
        kb[ci] = key;
    }
    asm volatile("s_waitcnt vmcnt(0) lgkmcnt(0)" ::: "memory");

    // ---- all-pairs rank: paired LDS reads, independent -> pipelined ----
    for (int ci = lane; ci < ct; ci += 64) {
        ull key = kb[ci];
        int rank = 0;
        int o = 0;
        for (; o + 8 <= ct; o += 8) {
            ull2 p0 = *(const ull2*)&kb[o];
            ull2 p1 = *(const ull2*)&kb[o + 2];
            ull2 p2 = *(const ull2*)&kb[o + 4];
            ull2 p3 = *(const ull2*)&kb[o + 6];
            rank += (p0.x < key) ? 1 : 0;
            rank += (p0.y < key) ? 1 : 0;
            rank += (p1.x < key) ? 1 : 0;
            rank += (p1.y < key) ? 1 : 0;
            rank += (p2.x < key) ? 1 : 0;
            rank += (p2.y < key) ? 1 : 0;
            rank += (p3.x < key) ? 1 : 0;
            rank += (p3.y < key) ? 1 : 0;
        }
        for (; o < ct; ++o) rank += (kb[o] < key) ? 1 : 0;
        if (rank < KNN) {
            unsigned db = (unsigned)(key >> 32);
            unsigned jj = (unsigned)key;
            size_t o0 = (size_t)row * KNN + rank;
            outd[o0] = __uint_as_float(db);
            outi[o0] = (jj == (unsigned)i) ? -1.f : (float)jj;
        }
    }
}

extern "C" void kernel_launch(void* const* d_in, const int* in_sizes, int n_in,
                              void* d_out, int out_size, void* d_ws, size_t ws_size,
                              hipStream_t stream) {
    const float* coords = (const float*)d_in[0];
    const float* mask   = (const float*)d_in[1];
    const float* w      = (const float*)d_in[2];
    const float* scale  = (const float*)d_in[3];
    const float* shift  = (const float*)d_in[4];

    int BN = in_sizes[1];          // B*N
    int N  = NATOMS;
    int B  = BN / N;

    float* ws0     = (float*)d_ws;
    float* cnt_all = ws0;                     // B (padded to 16)
    float* Aa      = ws0 + 16;                // B*128
    float* Bb      = Aa + B * EMB;            // B*128
    float* soa     = Bb + B * EMB;            // B*3*PADN

    float* out0 = (float*)d_out;                      // B*N*128
    float* outd = out0 + (size_t)B * N * EMB;         // B*N*30
    float* outi = outd + (size_t)B * N * KNN;         // B*N*30 (indices as float)

    prep_soa_kernel<<<B + B * GROUPS, 256, 0, stream>>>(mask, w, scale, shift, coords,
                                                        cnt_all, Aa, Bb, soa, B, N);
    knn_kernel<<<(B * N) / ROWS_PB, 256, 0, stream>>>(coords, soa, mask, cnt_all,
                                                      w, Aa, Bb, out0, outd, outi, B, N);
}

// Round 12
// 37.045 us; speedup vs baseline: 1.0428x; 1.0428x over previous
//
#include <hip/hip_runtime.h>
#include <stdint.h>

#define NTYPES 12
#define EMB 128
#define KNN 30
#define SEPS_F 1e-6f
#define LEPS_F 1e6f
#define NATOMS 4800
#define GROUPS 19           // 4-item groups per lane (76 items incl 1 stored pad)
#define PADN 4864           // GROUPS*256 floats per axis per batch
#define CAPH 64             // per-half candidate cap
#define ROWS_PB 4           // rows per block (4 waves: 2 row-pairs x 2 halves)
#define SENT16 0x7F7Fu      // bucket sentinel for masked items

typedef unsigned long long ull;
typedef float f32x2 __attribute__((ext_vector_type(2)));
typedef float f32x4 __attribute__((ext_vector_type(4)));

// ---- packed f32 ops (VOP3P, 2x rate) ----
__device__ __forceinline__ f32x2 pk_add(f32x2 a, f32x2 b) {
    f32x2 d; asm("v_pk_add_f32 %0, %1, %2" : "=v"(d) : "v"(a), "v"(b)); return d;
}
__device__ __forceinline__ f32x2 pk_mul(f32x2 a, f32x2 b) {
    f32x2 d; asm("v_pk_mul_f32 %0, %1, %2" : "=v"(d) : "v"(a), "v"(b)); return d;
}
__device__ __forceinline__ f32x2 pk_fma(f32x2 a, f32x2 b, f32x2 c) {
    f32x2 d; asm("v_pk_fma_f32 %0, %1, %2, %3" : "=v"(d) : "v"(a), "v"(b), "v"(c)); return d;
}
__device__ __forceinline__ unsigned pk_min_u16(unsigned a, unsigned b) {
    unsigned d; asm("v_pk_min_u16 %0, %1, %2" : "=v"(d) : "v"(a), "v"(b)); return d;
}

// packed filter d2 for 2 items (FMA ok: +2-bucket margin covers vs exact-rn)
__device__ __forceinline__ f32x2 d2pk(f32x2 x, f32x2 y, f32x2 z,
                                      f32x2 nqx, f32x2 nqy, f32x2 nqz) {
    f32x2 dx = pk_add(x, nqx), dy = pk_add(y, nqy), dz = pk_add(z, nqz);
    return pk_fma(dx, dx, pk_fma(dy, dy, pk_mul(dz, dz)));
}

// pack top-16 bits of two f32s: lo16 = even item (v.x), hi16 = odd item (v.y)
__device__ __forceinline__ unsigned bu(f32x2 v) {
    return __builtin_amdgcn_perm(__float_as_uint(v.y), __float_as_uint(v.x),
                                 0x07060302u);
}

// exact d2: plain rn ops, matches numpy bit-for-bit
__device__ __forceinline__ unsigned d2x(float x, float y, float z,
                                        float qx, float qy, float qz) {
    float dx = __fsub_rn(x, qx), dy = __fsub_rn(y, qy), dz = __fsub_rn(z, qz);
    float d2 = __fadd_rn(__fadd_rn(__fmul_rn(dx, dx), __fmul_rn(dy, dy)),
                         __fmul_rn(dz, dz));
    return __float_as_uint(d2);
}

// ---------------- prep (blocks 0..B-1) + SoA transpose (rest) — proven ----------------
__global__ __launch_bounds__(256) void prep_soa_kernel(const float* __restrict__ mask,
                                                       const float* __restrict__ w,
                                                       const float* __restrict__ scale,
                                                       const float* __restrict__ shift,
                                                       const float* __restrict__ coords,
                                                       float* __restrict__ cnt_all,
                                                       float* __restrict__ Aa,
                                                       float* __restrict__ Bb,
                                                       float* __restrict__ soa,
                                                       int B, int N) {
    if ((int)blockIdx.x < B) {
        __shared__ float lc[NTYPES];
        __shared__ float ltot;
        const int b = blockIdx.x;
        const int t = threadIdx.x;
        if (t < NTYPES) lc[t] = 0.f;
        if (t == 0) ltot = 0.f;
        __syncthreads();
        float s0 = 0.f, s1 = 0.f, s2 = 0.f, tot = 0.f;
        const float* mb = mask + (size_t)b * N;
#pragma unroll
        for (int base = 0; base < 21; base += 3) {
            int n0 = t + 256 * base;
            if (n0 < N) { float m = mb[n0]; s0 += m; tot += m; }
            int n1 = t + 256 * (base + 1);
            if (n1 < N) { float m = mb[n1]; s1 += m; tot += m; }
            int n2 = t + 256 * (base + 2);
            if (n2 < N) { float m = mb[n2]; s2 += m; tot += m; }
        }
        atomicAdd(&lc[t % NTYPES], s0);
        atomicAdd(&lc[(t + 4) % NTYPES], s1);
        atomicAdd(&lc[(t + 8) % NTYPES], s2);
        for (int s = 32; s >= 1; s >>= 1) tot += __shfl_xor(tot, s, 64);
        if ((t & 63) == 0) atomicAdd(&ltot, tot);
        __syncthreads();
        if (t < EMB) {
            const int d = t;
            float cnt = ltot;
            float c = (cnt == 0.f) ? 1.f : cnt;
            float mean = 0.f;
#pragma unroll
            for (int tt = 0; tt < NTYPES; ++tt) mean += w[tt * EMB + d] * lc[tt];
            mean /= c;
            float S = 0.f;
#pragma unroll
            for (int tt = 0; tt < NTYPES; ++tt) {
                float dv = w[tt * EMB + d] - mean;
                S += lc[tt] * dv * dv;
            }
            S += ((float)N - cnt) * mean * mean;
            float stdv = sqrtf(S / c + SEPS_F);
            float g = scale[d] / stdv;
            Aa[b * EMB + d] = g;
            Bb[b * EMB + d] = shift[d] - mean * g;
        }
        if (t == 0) cnt_all[b] = ltot;
    } else {
        int idx = blockIdx.x - B;
        const int b = idx / GROUPS;
        const int chunk = idx % GROUPS;
        const int j = chunk * 256 + threadIdx.x;   // 0..PADN-1
        float x, y, z;
        int slot;
        if (j < N) {
            int t = j >> 6, l = j & 63;
            slot = (t >> 2) * 256 + l * 4 + (t & 3);
            const float* cp = coords + ((size_t)b * N + j) * 3;
            x = cp[0]; y = cp[1]; z = cp[2];
        } else {
            int l = j - N;                          // stored pad item t = 75
            slot = (GROUPS - 1) * 256 + l * 4 + 3;
            x = y = z = 1.0e30f;                    // d2 -> +inf (bucket 0x7F80)
        }
        float* base = soa + (size_t)b * 3 * PADN;
        base[0 * PADN + slot] = x;
        base[1 * PADN + slot] = y;
        base[2 * PADN + slot] = z;
    }
}

// ---------------- exact 30-NN: 4 waves = 2 row-pairs x 2 halves ----------------
__global__ __launch_bounds__(256) void knn_kernel(const float* __restrict__ coords,
                                                  const float* __restrict__ soa,
                                                  const float* __restrict__ mask,
                                                  const float* __restrict__ cnt_all,
                                                  const float* __restrict__ w,
                                                  const float* __restrict__ Aa,
                                                  const float* __restrict__ Bb,
                                                  float* __restrict__ out0,
                                                  float* __restrict__ outd,
                                                  float* __restrict__ outi,
                                                  int B, int N) {
    __shared__ unsigned short lmx[ROWS_PB][2][64];  // lane-min buckets
    __shared__ unsigned candj[ROWS_PB][2][CAPH];    // candidate atom indices
    __shared__ int cnts[ROWS_PB][2];
    __shared__ ull keysS[ROWS_PB][2 * CAPH];        // exact keys for rank phase

    const int wv = threadIdx.x >> 6;
    const int lane = threadIdx.x & 63;
    const int pr = wv >> 1;                  // row-pair within block
    const int h = wv & 1;                    // item half
    const int r0 = blockIdx.x * ROWS_PB;
    const int b = r0 / N;                    // N % ROWS_PB == 0
    const int iA = (r0 + 2 * pr) - b * N;
    const int iB = iA + 1;

    const float* cb = coords + (size_t)b * N * 3;
    const float* mb = mask + (size_t)b * N;
    const bool allOnes = (cnt_all[b] == (float)N);

    const float qxA = cb[iA * 3], qyA = cb[iA * 3 + 1], qzA = cb[iA * 3 + 2];
    const float qxB = cb[iB * 3], qyB = cb[iB * 3 + 1], qzB = cb[iB * 3 + 2];
    const f32x2 nqxA = {-qxA, -qxA}, nqyA = {-qyA, -qyA}, nqzA = {-qzA, -qzA};
    const f32x2 nqxB = {-qxB, -qxB}, nqyB = {-qyB, -qyB}, nqzB = {-qzB, -qzB};

    const float* xs = soa + (size_t)b * 3 * PADN;
    const float* ys = xs + PADN;
    const float* zs = ys + PADN;
    const int loff = lane << 2;
    const int gbase = h ? 10 : 0;
    const int tbase = 4 * gbase;             // first item index of this half

    unsigned pkA[20], pkB[20];
    unsigned lmA2 = 0xFFFFFFFFu, lmB2 = 0xFFFFFFFFu;

#define PROC_GROUP(P, S0, S1)                                                     \
    {                                                                             \
        const int g = gbase + (P);                                                \
        const f32x4 xv = *(const f32x4*)(xs + g * 256 + loff);                    \
        const f32x4 yv = *(const f32x4*)(ys + g * 256 + loff);                    \
        const f32x4 zv = *(const f32x4*)(zs + g * 256 + loff);                    \
        const f32x2 xlo = {xv.x, xv.y}, xhi = {xv.z, xv.w};                       \
        const f32x2 ylo = {yv.x, yv.y}, yhi = {yv.z, yv.w};                       \
        const f32x2 zlo = {zv.x, zv.y}, zhi = {zv.z, zv.w};                       \
        unsigned a01 = bu(d2pk(xlo, ylo, zlo, nqxA, nqyA, nqzA));                 \
        unsigned a23 = bu(d2pk(xhi, yhi, zhi, nqxA, nqyA, nqzA));                 \
        unsigned b01 = bu(d2pk(xlo, ylo, zlo, nqxB, nqyB, nqzB));                 \
        unsigned b23 = bu(d2pk(xhi, yhi, zhi, nqxB, nqyB, nqzB));                 \
        if (!allOnes) {                                                           \
            const int t0 = 4 * g;                                                 \
            int j0 = (t0 + 0) * 64 + lane;                                        \
            int j1 = (t0 + 1) * 64 + lane;                                        \
            int j2 = (t0 + 2) * 64 + lane;                                        \
            int j3 = (t0 + 3) * 64 + lane;                                        \
            if (j0 < N && mb[j0] == 0.f) { a01 = (a01 & 0xFFFF0000u) | SENT16;    \
                                           b01 = (b01 & 0xFFFF0000u) | SENT16; }  \
            if (j1 < N && mb[j1] == 0.f) { a01 = (a01 & 0xFFFFu) | (SENT16 << 16);\
                                           b01 = (b01 & 0xFFFFu) | (SENT16 << 16);}\
            if (j2 < N && mb[j2] == 0.f) { a23 = (a23 & 0xFFFF0000u) | SENT16;    \
                                           b23 = (b23 & 0xFFFF0000u) | SENT16; }  \
            if (j3 < N && mb[j3] == 0.f) { a23 = (a23 & 0xFFFFu) | (SENT16 << 16);\
                                           b23 = (b23 & 0xFFFFu) | (SENT16 << 16);}\
        }                                                                         \
        lmA2 = pk_min_u16(pk_min_u16(lmA2, a01), a23);                            \
        lmB2 = pk_min_u16(pk_min_u16(lmB2, b01), b23);                            \
        pkA[S0] = a01; pkA[S1] = a23;                                             \
        pkB[S0] = b01; pkB[S1] = b23;                                             \
    }

    PROC_GROUP(0, 0, 1)   PROC_GROUP(1, 2, 3)   PROC_GROUP(2, 4, 5)
    PROC_GROUP(3, 6, 7)   PROC_GROUP(4, 8, 9)   PROC_GROUP(5, 10, 11)
    PROC_GROUP(6, 12, 13) PROC_GROUP(7, 14, 15) PROC_GROUP(8, 16, 17)
    if (h == 0) {
        PROC_GROUP(9, 18, 19)
    } else {
        pkA[18] = pkA[19] = 0xFFFFFFFFu;   // virtual pad pairs, never selected
        pkB[18] = pkB[19] = 0xFFFFFFFFu;
    }
#undef PROC_GROUP

    unsigned lmA16 = lmA2 & 0xFFFFu; { unsigned t2 = lmA2 >> 16; if (t2 < lmA16) lmA16 = t2; }
    unsigned lmB16 = lmB2 & 0xFFFFu; { unsigned t2 = lmB2 >> 16; if (t2 < lmB16) lmB16 = t2; }
    lmx[2 * pr][h][lane] = (unsigned short)lmA16;
    lmx[2 * pr + 1][h][lane] = (unsigned short)lmB16;
    __syncthreads();
    const unsigned ptA = lmx[2 * pr][h ^ 1][lane];
    const unsigned ptB = lmx[2 * pr + 1][h ^ 1][lane];

    // ---- dual certificate: 31st smallest of 128 lane-mins, 15 fixed iters ----
    unsigned loA = 0, hiA = 0x7F80u, loB = 0, hiB = 0x7F80u;
    for (int it = 0; it < 15; ++it) {
        unsigned mA = (loA + hiA) >> 1, mB = (loB + hiB) >> 1;
        int cA = __popcll(__ballot(lmA16 <= mA)) + __popcll(__ballot(ptA <= mA));
        int cB = __popcll(__ballot(lmB16 <= mB)) + __popcll(__ballot(ptB <= mB));
        if (cA >= 31) hiA = mA; else loA = mA + 1;
        if (cB >= 31) hiB = mB; else loB = mB + 1;
    }
    const unsigned TsA = hiA + 2, TsB = hiB + 2;   // +2: FMA-vs-exact margin

    // ---- compact (ascending j within half), rows A then B ----
    const ull lmaskLT = (1ull << lane) - 1ull;
    {
        unsigned* dst = candj[2 * pr][h];
        int c = 0;
#pragma unroll
        for (int p = 0; p < 20; ++p) {
            unsigned reg = pkA[p];
            bool pe = (reg & 0xFFFFu) <= TsA;
            ull be = __ballot(pe);
            if (pe) {
                int pos = c + __popcll(be & lmaskLT);
                if (pos < CAPH) dst[pos] = (unsigned)((tbase + 2 * p) * 64 + lane);
            }
            c += __popcll(be);
            bool po = (reg >> 16) <= TsA;
            ull bo = __ballot(po);
            if (po) {
                int pos = c + __popcll(bo & lmaskLT);
                if (pos < CAPH) dst[pos] = (unsigned)((tbase + 2 * p + 1) * 64 + lane);
            }
            c += __popcll(bo);
        }
        if (lane == 0) cnts[2 * pr][h] = (c > CAPH) ? CAPH : c;
    }
    {
        unsigned* dst = candj[2 * pr + 1][h];
        int c = 0;
#pragma unroll
        for (int p = 0; p < 20; ++p) {
            unsigned reg = pkB[p];
            bool pe = (reg & 0xFFFFu) <= TsB;
            ull be = __ballot(pe);
            if (pe) {
                int pos = c + __popcll(be & lmaskLT);
                if (pos < CAPH) dst[pos] = (unsigned)((tbase + 2 * p) * 64 + lane);
            }
            c += __popcll(be);
            bool po = (reg >> 16) <= TsB;
            ull bo = __ballot(po);
            if (po) {
                int pos = c + __popcll(bo & lmaskLT);
                if (pos < CAPH) dst[pos] = (unsigned)((tbase + 2 * p + 1) * 64 + lane);
            }
            c += __popcll(bo);
        }
        if (lane == 0) cnts[2 * pr + 1][h] = (c > CAPH) ? CAPH : c;
    }
    __syncthreads();

    // ================= phase E: wave wv owns row r0+wv entirely =================
    const int lr = wv;
    const int row = r0 + lr;
    const int i = row - b * N;
    const float mi = mb[i];

    // fused embedding write (float2/lane)
    {
        const int d0 = lane * 2;
        const float2 wvv = *(const float2*)(w + (i % NTYPES) * EMB + d0);
        const float2 av = *(const float2*)(Aa + b * EMB + d0);
        const float2 bv2 = *(const float2*)(Bb + b * EMB + d0);
        float2 o;
        o.x = (wvv.x * mi * av.x + bv2.x) * mi;
        o.y = (wvv.y * mi * av.y + bv2.y) * mi;
        *(float2*)(out0 + ((size_t)b * N + i) * EMB + d0) = o;
    }

    if (mi == 0.f) {    // masked row: forced outputs (after last barrier -> safe)
        if (lane < KNN) {
            size_t o0 = (size_t)row * KNN + lane;
            outd[o0] = LEPS_F;
            outi[o0] = -1.f;
        }
        return;
    }

    const int c0 = cnts[lr][0];
    const int ct = c0 + cnts[lr][1];        // 31 <= ct <= 128
    const float qx = cb[i * 3], qy = cb[i * 3 + 1], qz = cb[i * 3 + 2];

    // ---- exact keys (reference rounding) into LDS ----
    ull* kb = keysS[lr];
    for (int ci = lane; ci < ct; ci += 64) {
        unsigned j = (ci < c0) ? candj[lr][0][ci] : candj[lr][1][ci - c0];
        ull key = ~0ull;
        if (j < (unsigned)N) {
            const float* cj = cb + (size_t)j * 3;
            float mj = allOnes ? 1.f : mb[j];
            unsigned db = d2x(cj[0], cj[1], cj[2], qx, qy, qz);
            float dist = (j == (unsigned)i || mj == 0.f)
                             ? LEPS_F
                             : __fsqrt_rn(__fadd_rn(__uint_as_float(db), SEPS_F));
            key = ((ull)__float_as_uint(dist) << 32) | j;
        }
        kb[ci] = key;
    }
    asm volatile("s_waitcnt vmcnt(0) lgkmcnt(0)" ::: "memory");

    // ---- all-pairs rank: broadcast LDS reads, independent -> pipelined ----
    for (int ci = lane; ci < ct; ci += 64) {
        ull key = kb[ci];
        int rank = 0;
        int o = 0;
        for (; o + 8 <= ct; o += 8) {
            rank += (kb[o] < key) ? 1 : 0;
            rank += (kb[o + 1] < key) ? 1 : 0;
            rank += (kb[o + 2] < key) ? 1 : 0;
            rank += (kb[o + 3] < key) ? 1 : 0;
            rank += (kb[o + 4] < key) ? 1 : 0;
            rank += (kb[o + 5] < key) ? 1 : 0;
            rank += (kb[o + 6] < key) ? 1 : 0;
            rank += (kb[o + 7] < key) ? 1 : 0;
        }
        for (; o < ct; ++o) rank += (kb[o] < key) ? 1 : 0;
        if (rank < KNN) {
            unsigned db = (unsigned)(key >> 32);
            unsigned jj = (unsigned)key;
            size_t o0 = (size_t)row * KNN + rank;
            outd[o0] = __uint_as_float(db);
            outi[o0] = (jj == (unsigned)i) ? -1.f : (float)jj;
        }
    }
}

extern "C" void kernel_launch(void* const* d_in, const int* in_sizes, int n_in,
                              void* d_out, int out_size, void* d_ws, size_t ws_size,
                              hipStream_t stream) {
    const float* coords = (const float*)d_in[0];
    const float* mask   = (const float*)d_in[1];
    const float* w      = (const float*)d_in[2];
    const float* scale  = (const float*)d_in[3];
    const float* shift  = (const float*)d_in[4];

    int BN = in_sizes[1];          // B*N
    int N  = NATOMS;
    int B  = BN / N;

    float* ws0     = (float*)d_ws;
    float* cnt_all = ws0;                     // B (padded to 16)
    float* Aa      = ws0 + 16;                // B*128
    float* Bb      = Aa + B * EMB;            // B*128
    float* soa     = Bb + B * EMB;            // B*3*PADN

    float* out0 = (float*)d_out;                      // B*N*128
    float* outd = out0 + (size_t)B * N * EMB;         // B*N*30
    float* outi = outd + (size_t)B * N * KNN;         // B*N*30 (indices as float)

    prep_soa_kernel<<<B + B * GROUPS, 256, 0, stream>>>(mask, w, scale, shift, coords,
                                                        cnt_all, Aa, Bb, soa, B, N);
    knn_kernel<<<(B * N) / ROWS_PB, 256, 0, stream>>>(coords, soa, mask, cnt_all,
                                                      w, Aa, Bb, out0, outd, outi, B, N);
}